// Round 9
// baseline (294.633 us; speedup 1.0000x reference)
//
#include <hip/hip_runtime.h>

#define Bq 128
#define Sq 512
#define Cq 37
#define Dq 768
#define VST 40   // vhist row stride in floats; bp row stride uses Sq

static __device__ __forceinline__ float bcast(float v, int p) {
  return __int_as_float(__builtin_amdgcn_ds_bpermute(p << 2, __float_as_int(v)));
}

#define REP37(X) X(0)X(1)X(2)X(3)X(4)X(5)X(6)X(7)X(8)X(9)X(10)X(11)X(12)X(13) \
  X(14)X(15)X(16)X(17)X(18)X(19)X(20)X(21)X(22)X(23)X(24)X(25)X(26)X(27)X(28) \
  X(29)X(30)X(31)X(32)X(33)X(34)X(35)X(36)

// ---------------- Kernel 0: transpose W -> Wt[c][d] ----------------
__global__ __launch_bounds__(256) void prep_kernel(
    const float* __restrict__ W, float* __restrict__ Wt)
{
  for (int i = blockIdx.x * 256 + threadIdx.x; i < Dq * Cq; i += gridDim.x * 256) {
    int d = i / Cq, c = i % Cq;
    Wt[(size_t)c * Dq + d] = W[i];
  }
}

// ---------------- Kernel 1: emissions = x @ W + b ----------------
// 8 waves / 128 tokens per block; W tiles double-buffered in LDS (1 barrier
// per chunk, stage overlaps compute); x prefetched 1 chunk ahead into a
// parity-indexed register buffer (static indices).
#define EMIS_BODY(IT, CUR, NXT)                                               \
  {                                                                           \
    int itn = (IT) + 1;                                                       \
    if (itn < 24 && tid < 296) {                                              \
      int c = tid >> 3, q = tid & 7;                                          \
      *(float4*)(&wlds[NXT][c * 32 + q * 4]) =                                \
          *(const float4*)(Wt + (size_t)c * Dq + itn * 32 + q * 4);           \
    }                                                                         \
    int dn = (itn < 24 ? itn : (IT)) * 32;                                    \
    _Pragma("unroll")                                                         \
    for (int q = 0; q < 8; ++q)                                               \
      xbuf[NXT][q] = *(const float4*)(xr + dn + q * 4);                       \
    _Pragma("unroll")                                                         \
    for (int k = 0; k < 10; ++k) {                                            \
      int cc = cset + 4 * k;                                                  \
      if (cc < Cq) {                                                          \
        const float4* wr = (const float4*)(&wlds[CUR][cc * 32]);              \
        float a = acc[k];                                                     \
        _Pragma("unroll")                                                     \
        for (int q = 0; q < 8; ++q) {                                         \
          float4 w = wr[q];                                                   \
          a += xbuf[CUR][q].x * w.x; a += xbuf[CUR][q].y * w.y;               \
          a += xbuf[CUR][q].z * w.z; a += xbuf[CUR][q].w * w.w;               \
        }                                                                     \
        acc[k] = a;                                                           \
      }                                                                       \
    }                                                                         \
    __syncthreads();                                                          \
  }

__global__ __launch_bounds__(512) void emis_kernel(
    const float* __restrict__ x, const float* __restrict__ Wt,
    const float* __restrict__ bias, float* __restrict__ em)
{
  __shared__ float wlds[2][Cq * 32];                    // 2 x 4736 B
  int tid = threadIdx.x;
  int lane = tid & 63;
  int wq = __builtin_amdgcn_readfirstlane(tid >> 6);    // 0..7
  int cset = wq & 3;
  int tok = blockIdx.x * 128 + ((wq >> 2) << 6) + lane;
  const float* xr = x + (size_t)tok * Dq;
  float acc[10];
#pragma unroll
  for (int k = 0; k < 10; ++k) acc[k] = 0.f;

  if (tid < 296) {                                      // stage chunk 0 -> buf 0
    int c = tid >> 3, q = tid & 7;
    *(float4*)(&wlds[0][c * 32 + q * 4]) =
        *(const float4*)(Wt + (size_t)c * Dq + q * 4);
  }
  float4 xbuf[2][8];
#pragma unroll
  for (int q = 0; q < 8; ++q) xbuf[0][q] = *(const float4*)(xr + q * 4);
  __syncthreads();

#pragma unroll
  for (int itp = 0; itp < 12; ++itp) {
    EMIS_BODY(2 * itp, 0, 1)
    EMIS_BODY(2 * itp + 1, 1, 0)
  }
#pragma unroll
  for (int k = 0; k < 10; ++k) {
    int cc = cset + 4 * k;
    if (cc < Cq) em[(size_t)tok * Cq + cc] = acc[k] + bias[cc];
  }
}

// ---------------- Kernel 2: serial CRF, role-split across blocks ----------------
// Blocks 0-127: forward (exp domain). Blocks 128-255: viterbi + gold score.
// Each serial wave now owns a full CU (private LDS pipe) — isolates the
// R6-R8 LDS-pipe-contention hypothesis.
__global__ __launch_bounds__(256) void crf_serial_kernel(
    const float* __restrict__ em, const float* __restrict__ startv,
    const float* __restrict__ endv, const float* __restrict__ trans,
    const int* __restrict__ labels, const unsigned char* __restrict__ maskb,
    float* __restrict__ vhist, float* __restrict__ scorep,
    float* __restrict__ logZp, int* __restrict__ lenp, int* __restrict__ lastp)
{
  __shared__ float semm[Sq * Cq];          // 75,776 B
  __shared__ float sexch[64];
  int role = blockIdx.x >> 7, b = blockIdx.x & 127;
  int tid = threadIdx.x, wid = tid >> 6, lane = tid & 63;
  int cl = lane < Cq ? lane : Cq - 1;

  int esz4 = (maskb[1] == 0) ? 1 : 0;
  int len = 0;
#pragma unroll
  for (int k = 0; k < 8; ++k) {
    size_t t = (size_t)lane + (size_t)k * 64;
    unsigned char mb = esz4 ? maskb[((size_t)b * Sq + t) * 4] : maskb[(size_t)b * Sq + t];
    len += (mb != 0);
  }
#pragma unroll
  for (int off = 32; off; off >>= 1) len += __shfl_xor(len, off);

  const float4* src4 = (const float4*)(em + (size_t)b * Sq * Cq);
  float4* dst4 = (float4*)semm;
  for (int i = tid; i < (Sq * Cq) / 4; i += 256) dst4[i] = src4[i];
  __syncthreads();

  const float L2E = 1.4426950408889634f, LN2 = 0.6931471805599453f;

  if (role == 0 && wid == 0) {
    // ---- forward algorithm, exp domain (R8, unchanged math) ----
#define DECLE(i) float E##i = exp2f(trans[(i) * Cq + cl] * L2E);
    REP37(DECLE)
    float* sE = sexch;
    float a0 = (lane < Cq) ? (startv[cl] + semm[cl]) : -3.0e38f;
    float K0 = bcast(a0, 0);
    float ez = (lane < Cq) ? exp2f((a0 - K0) * L2E) : 0.f;
    int eacc = 0;
    float wA = exp2f(semm[1 * Cq + cl] * L2E), wB = exp2f(semm[2 * Cq + cl] * L2E);
    float wC = exp2f(semm[3 * Cq + cl] * L2E), wD = exp2f(semm[4 * Cq + cl] * L2E);
    for (int t = 1; t < len; ++t) {
      float w_cur = wA; wA = wB; wB = wC; wC = wD;
      int tn = (t + 4 < len) ? t + 4 : len - 1;
      wD = exp2f(semm[tn * Cq + cl] * L2E);
      sE[lane] = ez;                         // 1 ds_write_b32
      float gs[40];
      float4* gv = (float4*)gs;
      const float4* se4 = (const float4*)sE;
#pragma unroll
      for (int q = 0; q < 10; ++q) gv[q] = se4[q];   // 10x ds_read_b128 bcast
      int e0 = ((__float_as_int(gs[0]) >> 23) & 255) - 127;
      float scale = __int_as_float((127 - e0) << 23);  // 2^-e0 exact
      float s0 = 0.f, s1 = 0.f, s2 = 0.f, s3 = 0.f;
#define FACC(i) { \
      if (((i)&3)==0) s0 = fmaf(gs[i], E##i, s0); else if (((i)&3)==1) s1 = fmaf(gs[i], E##i, s1); \
      else if (((i)&3)==2) s2 = fmaf(gs[i], E##i, s2); else s3 = fmaf(gs[i], E##i, s3); }
      REP37(FACC)
      float dot = (s0 + s1) + (s2 + s3);
      ez = dot * (w_cur * scale);
      eacc += e0;
    }
    float xv = (lane < Cq) ? LN2 * (log2f(ez) + (float)eacc) + endv[cl] : -3.0e38f;
    float mm = xv;
#pragma unroll
    for (int off = 32; off; off >>= 1) mm = fmaxf(mm, __shfl_xor(mm, off));
    float es = exp2f((xv - mm) * L2E);
#pragma unroll
    for (int off = 32; off; off >>= 1) es += __shfl_xor(es, off);
    if (lane == 0) logZp[b] = mm + log2f(es) * LN2;
  } else if (role == 1 && wid == 0) {
    // ---- viterbi values (candidates in exact reference order) ----
#define DECLT(i) float T##i = trans[(i) * Cq + cl];
    REP37(DECLT)
    float* sV = sexch;
    float v = (lane < Cq) ? (startv[cl] + semm[cl]) : -3.0e38f;
    if (lane < Cq) vhist[((size_t)b * Sq) * VST + cl] = v;
    float emA = semm[1 * Cq + cl], emB = semm[2 * Cq + cl];
    float emC = semm[3 * Cq + cl], emD = semm[4 * Cq + cl];
    for (int t = 1; t < len; ++t) {
      float em_cur = emA; emA = emB; emB = emC; emC = emD;
      int tn = (t + 4 < len) ? t + 4 : len - 1;
      emD = semm[tn * Cq + cl];
      sV[lane] = v;                          // 1 ds_write_b32
      float vs[40];
      float4* vv4 = (float4*)vs;
      const float4* sv4 = (const float4*)sV;
#pragma unroll
      for (int q = 0; q < 10; ++q) vv4[q] = sv4[q];  // 10x ds_read_b128 bcast
      float b0 = -3.0e38f, b1 = -3.0e38f, b2 = -3.0e38f, b3 = -3.0e38f;
#define VMAX(i) { float cnd = vs[i] + T##i; \
      if (((i)&3)==0) b0 = fmaxf(b0, cnd); else if (((i)&3)==1) b1 = fmaxf(b1, cnd); \
      else if (((i)&3)==2) b2 = fmaxf(b2, cnd); else b3 = fmaxf(b3, cnd); }
      REP37(VMAX)
      float best = fmaxf(fmaxf(b0, b1), fmaxf(b2, b3));
      v = (lane < Cq) ? best + em_cur : -3.0e38f;
      if (lane < Cq) vhist[((size_t)b * Sq + t) * VST + cl] = v;
    }
    float xv = (lane < Cq) ? v + endv[cl] : -3.0e38f;
    int idx = (lane < Cq) ? lane : 1000;
#pragma unroll
    for (int off = 32; off; off >>= 1) {
      float xo = __shfl_xor(xv, off); int io = __shfl_xor(idx, off);
      if (xo > xv || (xo == xv && io < idx)) { xv = xo; idx = io; }
    }
    if (lane == 0) { lastp[b] = idx; lenp[b] = len; }
  } else if (role == 1 && wid == 1) {
    // ---- gold path score ----
    const int* lab = labels + (size_t)b * Sq;
    float sc = 0.f;
#pragma unroll
    for (int k = 0; k < 8; ++k) {
      int t = 1 + lane + k * 64;
      if (t < len) {
        int lp = lab[t - 1], lt = lab[t];
        sc += trans[lp * Cq + lt] + semm[t * Cq + lt];
      }
    }
#pragma unroll
    for (int off = 32; off; off >>= 1) sc += __shfl_xor(sc, off);
    if (lane == 0) {
      int l0 = lab[0], lf = lab[len - 1];
      scorep[b] = sc + startv[l0] + semm[l0] + endv[lf];
    }
  }
}

// ---------------- Kernel 3: backpointers (parallel recompute) ----------------
__global__ __launch_bounds__(256) void crf_bp_kernel(
    const float* __restrict__ vhist, const float* __restrict__ trans,
    const int* __restrict__ lenp, unsigned char* __restrict__ bp)
{
  int b = blockIdx.x >> 2, chunk = blockIdx.x & 3;
  int wid = threadIdx.x >> 6, lane = threadIdx.x & 63;
  int cl = lane < Cq ? lane : Cq - 1;
  int len = lenp[b];
  REP37(DECLT)
  int tend = 1 + (chunk + 1) * 128; if (tend > len) tend = len;
  int rl9 = lane < VST ? lane : VST - 1;
  for (int t = 1 + chunk * 128 + wid; t < tend; t += 4) {
    float vr = vhist[((size_t)b * Sq + (t - 1)) * VST + rl9];
#define BCASTB(i) float br##i = bcast(vr, (i));
    REP37(BCASTB)
    float best = -3.0e38f; int bi = 0;
#define BARG(i) { float cnd = br##i + T##i; if (cnd > best) { best = cnd; bi = (i); } }
    REP37(BARG)                             // ascending + strict '>' => first-index tie-break
    if (lane < Cq) bp[((size_t)b * VST + cl) * Sq + t] = (unsigned char)bi;
  }
}

// ---------------- Kernel 4: register-resident backtrack ----------------
__global__ __launch_bounds__(64) void crf_back_kernel(
    const unsigned char* __restrict__ bp, const int* __restrict__ lenp,
    const int* __restrict__ lastp, float* __restrict__ outp)
{
  int b = blockIdx.x, lane = threadIdx.x;
  int len = __builtin_amdgcn_readfirstlane(lenp[b]);
  int tag = __builtin_amdgcn_readfirstlane(lastp[b]);
  int row = lane < VST ? lane : VST - 1;
  const uint4* src = (const uint4*)(bp + ((size_t)b * VST + row) * Sq);
  unsigned r[128];
#pragma unroll
  for (int k = 0; k < 32; ++k) {
    uint4 q = src[k];
    r[4 * k] = q.x; r[4 * k + 1] = q.y; r[4 * k + 2] = q.z; r[4 * k + 3] = q.w;
  }
  unsigned vt[8];
#pragma unroll
  for (int j = 0; j < 8; ++j) vt[j] = 0u;
  vt[7] = (lane == 63) ? (unsigned)tag : vt[7];
#pragma unroll
  for (int t = 510; t >= 0; --t) {
    int word = __builtin_amdgcn_readlane((int)r[(t + 1) >> 2], tag);
    int nt = (word >> (((t + 1) & 3) * 8)) & 0xff;
    tag = (t + 1 < len) ? nt : tag;
    vt[t >> 6] = (lane == (t & 63)) ? (unsigned)tag : vt[t >> 6];
  }
#pragma unroll
  for (int j = 0; j < 8; ++j) {
    int t = j * 64 + lane;
    float o = (t < len) ? (float)(int)vt[j] : 36.0f;
    outp[(size_t)b * Sq + t] = o;
  }
}

// ---------------- Kernel 5: reduce ll partials ----------------
__global__ __launch_bounds__(64) void ll_reduce_kernel(
    const float* __restrict__ scorep, const float* __restrict__ logZp,
    float* __restrict__ outp)
{
  int lane = threadIdx.x;
  float s = (scorep[lane] - logZp[lane]) + (scorep[lane + 64] - logZp[lane + 64]);
#pragma unroll
  for (int off = 32; off; off >>= 1) s += __shfl_xor(s, off);
  if (lane == 0) outp[0] = s;
}

extern "C" void kernel_launch(void* const* d_in, const int* in_sizes, int n_in,
                              void* d_out, int out_size, void* d_ws, size_t ws_size,
                              hipStream_t stream)
{
  const float* x      = (const float*)d_in[0];
  const float* W      = (const float*)d_in[1];
  const float* bias   = (const float*)d_in[2];
  const float* startv = (const float*)d_in[3];
  const float* endv   = (const float*)d_in[4];
  const float* trans  = (const float*)d_in[5];
  const int*   labels = (const int*)d_in[6];
  const unsigned char* maskb = (const unsigned char*)d_in[7];
  float* out = (float*)d_out;

  char* ws = (char*)d_ws;
  float* em            = (float*)(ws);                    // 9,699,328 B
  float* vhist         = (float*)(ws + 9699328);          // 10,485,760 B
  unsigned char* bpbuf = (unsigned char*)(ws + 20185088); // 2,621,440 B
  float* scorep        = (float*)(ws + 22806528);         // 512 B
  float* logZp         = (float*)(ws + 22807040);         // 512 B
  int*   lenp          = (int*)(ws + 22807552);           // 512 B
  int*   lastp         = (int*)(ws + 22808064);           // 512 B
  float* Wt            = (float*)(ws + 22808576);         // 113,664 B

  prep_kernel<<<28, 256, 0, stream>>>(W, Wt);
  emis_kernel<<<512, 512, 0, stream>>>(x, Wt, bias, em);
  crf_serial_kernel<<<256, 256, 0, stream>>>(em, startv, endv, trans, labels, maskb,
                                             vhist, scorep, logZp, lenp, lastp);
  crf_bp_kernel<<<512, 256, 0, stream>>>(vhist, trans, lenp, bpbuf);
  crf_back_kernel<<<128, 64, 0, stream>>>(bpbuf, lenp, lastp, out + 1);
  ll_reduce_kernel<<<1, 64, 0, stream>>>(scorep, logZp, out);
}